// Round 10
// baseline (694.856 us; speedup 1.0000x reference)
//
#include <hip/hip_runtime.h>
#include <hip/hip_cooperative_groups.h>
#include <math.h>

namespace cg = cooperative_groups;

// ---------------- workspace layout (bytes) ----------------
#define O_SMALL  (0)
#define O_RPD    (256*1024)
#define O_RPS    (512*1024)
#define O_DINV   (768*1024)
#define O_Y      (1024*1024)
#define O_RELW   (1280*1024)
#define O_REL    (1536*1024)
#define O_BTD    (1792*1024)
#define O_BTS    (1800*1024)
#define O_BSD    (1808*1024)
#define O_BSS    (1816*1024)
#define O_PART   (2048*1024)          // GRID*132*4 <= 540KB
#define O_XS     (2816*1024)          // N float4
#define O_G1     (3840*1024)          // N float4
#define O_GHD    (5120*1024)          // NB*NCH ints
#define O_GHS    (5632*1024)
#define O_GOD    (6144*1024)
#define O_GOS    (6656*1024)
#define O_SRTD   (7168*1024)          // E uints
#define O_SRTS   (10496*1024)
#define O_COLD   (13824*1024)
#define O_COLS   (17152*1024)
// small[]: [0..127] w2qk  [128] bias  [132..259] S  [260] R  [264..391] newT

#define NCH 512                        // chunks per orientation

struct MegaArgs {
    const float *x; const int *eidx; const float *trainOT;
    const float *W1, *b1, *W2, *b2, *Wq, *bq, *Wk, *bk, *Wv, *bv, *Ws, *bs;
    float *out; int out_n, N, E, NB, CS;
    int *rpD, *rpS; float *dinv, *small, *y, *relw, *rel;
    int *ghD, *ghS, *goD, *goS, *btD, *btS, *bsD, *bsS;
    float *part; float4 *xs4, *g1;
    unsigned int *srtD, *srtS; int *colD, *colS;
};

static __device__ __forceinline__ int exclScan256(int v, volatile int* lds, int t) {
    int lane = t & 63, wid = t >> 6;
    int incl = v;
#pragma unroll
    for (int off = 1; off < 64; off <<= 1) {
        int n = __shfl_up(incl, off);
        if (lane >= off) incl += n;
    }
    if (lane == 63) lds[wid] = incl;
    __syncthreads();
    if (t == 0) {
        int s = 0;
#pragma unroll
        for (int i = 0; i < 4; ++i) { int x2 = lds[i]; lds[i] = s; s += x2; }
    }
    __syncthreads();
    return lds[wid] + incl - v;
}

__global__ __launch_bounds__(256, 4) void k_mega(MegaArgs a) {
    cg::grid_group grid = cg::this_grid();
    const int t = threadIdx.x;
    const int G = gridDim.x;
    const int NB = a.NB, N = a.N, E = a.E, CS = a.CS;

    __shared__ int lh[256];
    __shared__ int li2[256];
    __shared__ int lds1[4];
    __shared__ float fred[256];
    __shared__ float W1s[384];
    __shared__ float b1s[128];
    __shared__ float sS[4][132];
    __shared__ float kv[64];
    __shared__ float wqk[128];

    // ======== PA: per-chunk bucket histograms (both orientations) ========
    for (int task = blockIdx.x; task < 2 * NCH; task += G) {
        int o = task >> 9, c = task & (NCH - 1);
        const int* arr = o ? a.eidx : (a.eidx + E);        // o=0: dst, o=1: src
        int* gh = o ? a.ghS : a.ghD;
        lh[t] = 0; __syncthreads();
        int s = c * CS, e = min(E, s + CS);
        for (int i = s + t; i < e; i += 256) atomicAdd(&lh[arr[i] >> 8], 1);
        __syncthreads();
        if (t < NB) gh[t * NCH + c] = lh[t];
        __syncthreads();
    }
    grid.sync();

    // ======== PB1: bucket totals (row-sums) + tiny1 as spare task ========
    for (int task = blockIdx.x; task < 2 * NB + 1; task += G) {
        if (task < 2 * NB) {
            int o = task >= NB; int nb = o ? task - NB : task;
            const int* gh = o ? a.ghS : a.ghD;
            int* bt = o ? a.btS : a.btD;
            int v = 0;
            for (int i = t; i < NCH; i += 256) v += gh[nb * NCH + i];
            lh[t] = v; __syncthreads();
            for (int off = 128; off >= 1; off >>= 1) { if (t < off) lh[t] += lh[t + off]; __syncthreads(); }
            if (t == 0) bt[nb] = lh[0];
            __syncthreads();
        } else {
            // tiny1: w2qk & bias
            if (t < 64) {
                float acc = a.bk[t];
                for (int j = 0; j < 128; ++j) acc += a.trainOT[j] * a.Wk[j * 64 + t];
                kv[t] = acc;
            }
            __syncthreads();
            if (t < 128) {
                float aq = 0.f;
                for (int c2 = 0; c2 < 64; ++c2) aq += a.Wq[t * 64 + c2] * kv[c2];
                wqk[t] = aq;
            }
            fred[t] = (t < 64) ? a.bq[t] * kv[t] : 0.f;
            __syncthreads();
            for (int off = 128; off >= 1; off >>= 1) { if (t < off) fred[t] += fred[t + off]; __syncthreads(); }
            float bqs = fred[0];
            __syncthreads();
            if (t < 128) {
                float a2 = 0.f;
                for (int j = 0; j < 128; ++j) a2 += a.W2[t * 128 + j] * wqk[j];
                a.small[t] = a2;
            }
            fred[t] = (t < 128) ? a.b2[t] * wqk[t] : 0.f;
            __syncthreads();
            for (int off = 128; off >= 1; off >>= 1) { if (t < off) fred[t] += fred[t + off]; __syncthreads(); }
            if (t == 0) a.small[128] = bqs + fred[0];
            __syncthreads();
        }
    }
    grid.sync();

    // ======== PB2: bucket starts + per-bucket chunk-offset scans ========
    for (int task = blockIdx.x; task < 2 * NB; task += G) {
        int o = task >= NB; int nb = o ? task - NB : task;
        const int* bt = o ? a.btS : a.btD;
        const int* gh = o ? a.ghS : a.ghD;
        int* go = o ? a.goS : a.goD;
        int* bsx = o ? a.bsS : a.bsD;
        lh[t] = (t < nb) ? bt[t] : 0; __syncthreads();
        for (int off = 128; off >= 1; off >>= 1) { if (t < off) lh[t] += lh[t + off]; __syncthreads(); }
        int base = lh[0];
        __syncthreads();
        if (t == 0) { bsx[nb] = base; if (nb == NB - 1) bsx[NB] = E; }
        int g0 = gh[nb * NCH + 2 * t], g1e = gh[nb * NCH + 2 * t + 1];
        int ex = exclScan256(g0 + g1e, lds1, t);
        go[nb * NCH + 2 * t] = base + ex;
        go[nb * NCH + 2 * t + 1] = base + ex + g0;
        __syncthreads();
    }
    grid.sync();

    // ======== PC: scatter edges into bucket-sorted runs ========
    for (int task = blockIdx.x; task < 2 * NCH; task += G) {
        int o = task >> 9, c = task & (NCH - 1);
        const int* key = o ? a.eidx : (a.eidx + E);
        const int* val = o ? (a.eidx + E) : a.eidx;
        const int* go = o ? a.goS : a.goD;
        unsigned int* srt = o ? a.srtS : a.srtD;
        if (t < NB) li2[t] = go[t * NCH + c];
        __syncthreads();
        int s = c * CS, e = min(E, s + CS);
        for (int i = s + t; i < e; i += 256) {
            int k = key[i];
            int pos = atomicAdd(&li2[k >> 8], 1);
            srt[pos] = ((unsigned int)(k & 255) << 16) | (unsigned int)val[i];
        }
        __syncthreads();
    }
    grid.sync();

    // ======== PD: per-bucket degree + row_ptr + CSR fill; fwd: dinv/xs4 ========
    for (int task = blockIdx.x; task < 2 * NB; task += G) {
        int o = task >= NB; int nb = o ? task - NB : task;
        const unsigned int* srt = o ? a.srtS : a.srtD;
        const int* bst = o ? a.bsS : a.bsD;
        int* rp = o ? a.rpS : a.rpD;
        int* col = o ? a.colS : a.colD;
        lh[t] = 0; __syncthreads();
        int s = bst[nb], e = bst[nb + 1];
        for (int i = s + t; i < e; i += 256) atomicAdd(&lh[srt[i] >> 16], 1);
        __syncthreads();
        int c = lh[t];
        int cx = exclScan256(c, lds1, t);
        int rpv = s + cx;
        int node = (nb << 8) + t;
        rp[node] = rpv;
        li2[t] = rpv;
        if (!o && node < N) {
            float d = rsqrtf((float)(c + 1));   // +1 self-loop
            a.dinv[node] = d;
            float4 v;
            v.x = a.x[node * 3] * d; v.y = a.x[node * 3 + 1] * d; v.z = a.x[node * 3 + 2] * d; v.w = 0.f;
            a.xs4[node] = v;
        }
        __syncthreads();
        for (int i = s + t; i < e; i += 256) {
            unsigned int v = srt[i];
            int p = atomicAdd(&li2[v >> 16], 1);
            col[p] = (int)(v & 0xffffu);
        }
        __syncthreads();
    }
    grid.sync();

    // ======== PE: k_y — agg features over dst-CSR; store g1, y ========
    int ngrp = (N + 15) >> 4;
    for (int task = blockIdx.x; task < ngrp; task += G) {
        int sub = t & 15;
        int node = task * 16 + (t >> 4);
        if (node < N) {
            float di = a.dinv[node];
            int s = a.rpD[node], e = a.rpD[node + 1];
            float a0 = 0.f, a1 = 0.f, a2 = 0.f;
            for (int j = s + sub; j < e; j += 16) {
                float4 xv = a.xs4[a.colD[j]];
                a0 += xv.x; a1 += xv.y; a2 += xv.z;
            }
            if (sub == 0) { float4 xv = a.xs4[node]; a0 += xv.x; a1 += xv.y; a2 += xv.z; }
#pragma unroll
            for (int off = 1; off < 16; off <<= 1) {
                a0 += __shfl_xor(a0, off);
                a1 += __shfl_xor(a1, off);
                a2 += __shfl_xor(a2, off);
            }
            a0 *= di; a1 *= di; a2 *= di;
            float yl = 0.f;
#pragma unroll
            for (int m = 0; m < 8; ++m) {
                int c = sub * 8 + m;
                float h = fmaxf(a0 * a.W1[c] + a1 * a.W1[128 + c] + a2 * a.W1[256 + c] + a.b1[c], 0.f);
                yl += h * a.small[c];
            }
#pragma unroll
            for (int off = 1; off < 16; off <<= 1) yl += __shfl_xor(yl, off);
            if (sub == 0) {
                a.y[node] = yl * di;
                float4 gv; gv.x = a0; gv.y = a1; gv.z = a2; gv.w = di;
                a.g1[node] = gv;
            }
        }
    }
    grid.sync();

    // ======== PF: k_dv — agg y over dst-CSR -> rel/relw ========
    for (int task = blockIdx.x; task < ngrp; task += G) {
        int sub = t & 15;
        int node = task * 16 + (t >> 4);
        if (node < N) {
            float di = a.dinv[node];
            int s = a.rpD[node], e = a.rpD[node + 1];
            float acc = (sub == 0) ? a.y[node] : 0.f;
            for (int j = s + sub; j < e; j += 16) acc += a.y[a.colD[j]];
#pragma unroll
            for (int off = 1; off < 16; off <<= 1) acc += __shfl_xor(acc, off);
            float z = (acc * di + a.small[128]) * 0.125f;
            float r = 1.f / (1.f + __expf(-z));
            if (sub == 0) { a.rel[node] = r; a.relw[node] = r * di; }
        }
    }
    grid.sync();

    // ======== PG: k_z — agg relw over src-CSR; S,R partials ========
    if (t < 128) { W1s[t] = a.W1[t]; W1s[128 + t] = a.W1[128 + t]; W1s[256 + t] = a.W1[256 + t];
                   b1s[t] = a.b1[t]; }
    __syncthreads();
    {
        int lane = t & 63, wid = t >> 6, sub = lane & 15;
        float acc[8];
#pragma unroll
        for (int m = 0; m < 8; ++m) acc[m] = 0.f;
        float Racc = 0.f;
        for (int node = blockIdx.x * 16 + (t >> 4); node < N; node += G * 16) {
            int s = a.rpS[node], e = a.rpS[node + 1];
            float w = (sub == 0) ? a.relw[node] : 0.f;
            for (int j = s + sub; j < e; j += 16) w += a.relw[a.colS[j]];
#pragma unroll
            for (int off = 1; off < 16; off <<= 1) w += __shfl_xor(w, off);
            float4 gv = a.g1[node];
            float zw = w * gv.w;
#pragma unroll
            for (int m = 0; m < 8; ++m) {
                int c = sub * 8 + m;
                float h = fmaxf(gv.x * W1s[c] + gv.y * W1s[128 + c] + gv.z * W1s[256 + c] + b1s[c], 0.f);
                acc[m] += zw * h;
            }
            if (sub == 0) Racc += a.rel[node];
        }
#pragma unroll
        for (int m = 0; m < 8; ++m) {
            acc[m] += __shfl_xor(acc[m], 16);
            acc[m] += __shfl_xor(acc[m], 32);
        }
        Racc += __shfl_xor(Racc, 16);
        Racc += __shfl_xor(Racc, 32);
        if (lane < 16) {
#pragma unroll
            for (int m = 0; m < 8; ++m) sS[wid][sub * 8 + m] = acc[m];
        }
        if (lane == 0) sS[wid][128] = Racc;
        __syncthreads();
        if (t < 129) a.part[blockIdx.x * 132 + t] = sS[0][t] + sS[1][t] + sS[2][t] + sS[3][t];
        __syncthreads();
    }
    grid.sync();

    // ======== PH: reduce part -> small[132..260] ========
    for (int c = blockIdx.x; c < 129; c += G) {
        float acc = 0.f;
        for (int b = t; b < G; b += 256) acc += a.part[b * 132 + c];
        fred[t] = acc; __syncthreads();
        for (int off = 128; off >= 1; off >>= 1) { if (t < off) fred[t] += fred[t + off]; __syncthreads(); }
        if (t == 0) a.small[132 + c] = fred[0];
        __syncthreads();
    }
    grid.sync();

    // ======== PI: tail matvecs (block 0) ========
    if (blockIdx.x == 0) {
        int o = t & 127, sl = t >> 7;         // 2 K-slices of 64
        float R = a.small[260];
        float acc = 0.f;
        for (int j = sl * 64; j < sl * 64 + 64; ++j) acc += a.small[132 + j] * a.W2[j * 128 + o];
        fred[t] = acc; __syncthreads();
        if (t < 128) wqk[t] = R * a.b2[t] + fred[t] + fred[t + 128];
        __syncthreads();
        float acc2 = 0.f;
        for (int j = sl * 64; j < sl * 64 + 64; ++j) acc2 += wqk[j] * a.Wv[j * 128 + o];
        fred[t] = acc2; __syncthreads();
        if (t < 128) {
            float nt = a.trainOT[t] + R * a.bv[t] + fred[t] + fred[t + 128];
            a.small[264 + t] = nt;
            a.out[a.out_n + t] = nt;
        }
    }
    grid.sync();

    // ======== PJ: speak — out[j] = newT @ Ws[:,j] + bs[j] (4 K-slices in-block) ========
    if (t < 128) b1s[t] = a.small[264 + t];
    __syncthreads();
    int ntile = (a.out_n + 63) >> 6;
    for (int task = blockIdx.x; task < ntile; task += G) {
        int j = task * 64 + (t & 63);
        int sl = t >> 6;                       // 4 slices of 32
        float acc = 0.f;
        if (j < a.out_n) {
            const float* w = a.Ws + (size_t)(sl * 32) * a.out_n + j;
            for (int k = 0; k < 32; ++k) acc += b1s[sl * 32 + k] * w[(size_t)k * a.out_n];
        }
        fred[t] = acc; __syncthreads();
        if (t < 64 && j < a.out_n)
            a.out[j] = fred[t] + fred[t + 64] + fred[t + 128] + fred[t + 192] + a.bs[j];
        __syncthreads();
    }
}

extern "C" void kernel_launch(void* const* d_in, const int* in_sizes, int n_in,
                              void* d_out, int out_size, void* d_ws, size_t ws_size,
                              hipStream_t stream) {
    MegaArgs a;
    a.x = (const float*)d_in[0];
    a.eidx = (const int*)d_in[1];
    a.trainOT = (const float*)d_in[2];
    a.W1 = (const float*)d_in[3];  a.b1 = (const float*)d_in[4];
    a.W2 = (const float*)d_in[5];  a.b2 = (const float*)d_in[6];
    a.Wq = (const float*)d_in[7];  a.bq = (const float*)d_in[8];
    a.Wk = (const float*)d_in[9];  a.bk = (const float*)d_in[10];
    a.Wv = (const float*)d_in[11]; a.bv = (const float*)d_in[12];
    a.Ws = (const float*)d_in[13]; a.bs = (const float*)d_in[14];
    a.out = (float*)d_out;
    a.N = in_sizes[0] / 3;
    a.E = in_sizes[1] / 2;
    a.out_n = out_size - 128;
    a.NB = (a.N + 255) >> 8;
    a.CS = (a.E + NCH - 1) / NCH;

    char* ws = (char*)d_ws;
    a.small = (float*)(ws + O_SMALL);
    a.rpD = (int*)(ws + O_RPD);   a.rpS = (int*)(ws + O_RPS);
    a.dinv = (float*)(ws + O_DINV);
    a.y = (float*)(ws + O_Y);  a.relw = (float*)(ws + O_RELW);  a.rel = (float*)(ws + O_REL);
    a.btD = (int*)(ws + O_BTD);   a.btS = (int*)(ws + O_BTS);
    a.bsD = (int*)(ws + O_BSD);   a.bsS = (int*)(ws + O_BSS);
    a.part = (float*)(ws + O_PART);
    a.xs4 = (float4*)(ws + O_XS); a.g1 = (float4*)(ws + O_G1);
    a.ghD = (int*)(ws + O_GHD);   a.ghS = (int*)(ws + O_GHS);
    a.goD = (int*)(ws + O_GOD);   a.goS = (int*)(ws + O_GOS);
    a.srtD = (unsigned int*)(ws + O_SRTD);
    a.srtS = (unsigned int*)(ws + O_SRTS);
    a.colD = (int*)(ws + O_COLD); a.colS = (int*)(ws + O_COLS);

    int nbpc = 0;
    hipOccupancyMaxActiveBlocksPerMultiprocessor(&nbpc, k_mega, 256, 0);
    if (nbpc < 1) nbpc = 1;
    hipDeviceProp_t props;
    int dev = 0;
    hipGetDevice(&dev);
    hipGetDeviceProperties(&props, dev);
    int grid = nbpc * props.multiProcessorCount;
    if (grid > 1024) grid = 1024;
    if (grid < 1) grid = 1;

    void* kargs[] = { (void*)&a };
    hipLaunchCooperativeKernel((void*)k_mega, dim3(grid), dim3(256), kargs, 0, stream);
}

// Round 11
// 125.389 us; speedup vs baseline: 5.5416x; 5.5416x over previous
//
#include <hip/hip_runtime.h>
#include <math.h>

// ---------------- workspace layout (bytes) ----------------
#define O_SMALL  (0)
#define O_RPD    (256*1024)
#define O_RPS    (512*1024)
#define O_DINV   (768*1024)
#define O_Y      (1024*1024)
#define O_RELW   (1280*1024)
#define O_REL    (1536*1024)
#define O_BSD    (1792*1024)          // NB+1 ints
#define O_BSS    (1800*1024)
#define O_PART   (2048*1024)          // ZB*132*4 = 135KB
#define O_XS     (2816*1024)          // N float4
#define O_G1     (3840*1024)          // N float4
#define O_GHD    (5120*1024)          // NB*NCH ints = 401KB
#define O_GHS    (5632*1024)
#define O_GOD    (6144*1024)
#define O_GOS    (6656*1024)
#define O_SRTD   (7168*1024)          // E uints = 3.2MB
#define O_SRTS   (10496*1024)
#define O_COLD   (13824*1024)
#define O_COLS   (17152*1024)
// small[]: [0..127] w2qk  [128] bias  [264..391] newT

#define NCH 512
#define ZB  256

static __device__ __forceinline__ int exclScan256(int v, volatile int* lds, int t) {
    int lane = t & 63, wid = t >> 6;
    int incl = v;
#pragma unroll
    for (int off = 1; off < 64; off <<= 1) {
        int n = __shfl_up(incl, off);
        if (lane >= off) incl += n;
    }
    if (lane == 63) lds[wid] = incl;
    __syncthreads();
    if (t == 0) {
        int s = 0;
#pragma unroll
        for (int i = 0; i < 4; ++i) { int x2 = lds[i]; lds[i] = s; s += x2; }
    }
    __syncthreads();
    return lds[wid] + incl - v;
}

// ---------------- A1: per-chunk bucket histograms (both orientations) ----------------
__global__ void k_hist(const int* __restrict__ eidx, int* __restrict__ ghD,
                       int* __restrict__ ghS, int E, int CS, int NB) {
    __shared__ int lh[256];
    int c = blockIdx.x, t = threadIdx.x;
    const int* arr = blockIdx.y ? eidx : (eidx + E);      // y=0: dst, y=1: src
    int* gh = blockIdx.y ? ghS : ghD;
    lh[t] = 0; __syncthreads();
    int s = c * CS, e = min(E, s + CS);
    for (int i = s + t; i < e; i += 256) atomicAdd(&lh[arr[i] >> 8], 1);
    __syncthreads();
    if (t < NB) gh[t * NCH + c] = lh[t];                  // transposed: [bucket][chunk]
}

// ---------------- A2: per-bucket base (parallel row-sums) + chunk-offset scan; spare: tiny1 --
__global__ void k_goff(const int* __restrict__ ghD, const int* __restrict__ ghS,
                       int* __restrict__ goD, int* __restrict__ goS,
                       int* __restrict__ bsD, int* __restrict__ bsS,
                       const float* __restrict__ trainOT, const float* __restrict__ Wq,
                       const float* __restrict__ bq, const float* __restrict__ Wk,
                       const float* __restrict__ bk, const float* __restrict__ W2,
                       const float* __restrict__ b2, float* __restrict__ small,
                       int E, int NB) {
    __shared__ int lred[256];
    __shared__ int lds1[4];
    __shared__ float kv[64];
    __shared__ float wqk[128];
    __shared__ float fred[256];
    int nb = blockIdx.x, t = threadIdx.x;
    if (nb == NB) {
        if (blockIdx.y) return;
        // ---- tiny1: w2qk & bias ----
        if (t < 64) {
            float acc = bk[t];
            for (int j = 0; j < 128; ++j) acc += trainOT[j] * Wk[j * 64 + t];
            kv[t] = acc;
        }
        __syncthreads();
        if (t < 128) {
            float aq = 0.f;
            for (int c2 = 0; c2 < 64; ++c2) aq += Wq[t * 64 + c2] * kv[c2];
            wqk[t] = aq;
        }
        fred[t] = (t < 64) ? bq[t] * kv[t] : 0.f;
        __syncthreads();
        for (int off = 128; off >= 1; off >>= 1) { if (t < off) fred[t] += fred[t + off]; __syncthreads(); }
        float bqs = fred[0];
        __syncthreads();
        if (t < 128) {
            float a2 = 0.f;
            for (int j = 0; j < 128; ++j) a2 += W2[t * 128 + j] * wqk[j];
            small[t] = a2;
        }
        fred[t] = (t < 128) ? b2[t] * wqk[t] : 0.f;
        __syncthreads();
        for (int off = 128; off >= 1; off >>= 1) { if (t < off) fred[t] += fred[t + off]; __syncthreads(); }
        if (t == 0) small[128] = bqs + fred[0];
        return;
    }
    const int* gh = blockIdx.y ? ghS : ghD;
    int* go = blockIdx.y ? goS : goD;
    int* bs = blockIdx.y ? bsS : bsD;
    // base = sum of bucket totals below nb (parallel row-sums, L2-resident)
    int rs = 0;
    if (t < nb) {
        const int4* row = reinterpret_cast<const int4*>(gh + t * NCH);
        for (int i = 0; i < NCH / 4; ++i) { int4 p = row[i]; rs += p.x + p.y + p.z + p.w; }
    }
    lred[t] = rs; __syncthreads();
    for (int off = 128; off >= 1; off >>= 1) { if (t < off) lred[t] += lred[t + off]; __syncthreads(); }
    int base = lred[0];
    __syncthreads();
    if (t == 0) { bs[nb] = base; if (nb == NB - 1) bs[NB] = E; }
    // exclusive scan of own row (2 chunks per thread)
    int g0 = gh[nb * NCH + 2 * t], g1 = gh[nb * NCH + 2 * t + 1];
    int ex = exclScan256(g0 + g1, lds1, t);
    go[nb * NCH + 2 * t] = base + ex;
    go[nb * NCH + 2 * t + 1] = base + ex + g0;
}

// ---------------- A3: scatter edges into bucket-sorted runs ----------------
__global__ void k_scatter(const int* __restrict__ eidx, const int* __restrict__ goD,
                          const int* __restrict__ goS, unsigned int* __restrict__ srtD,
                          unsigned int* __restrict__ srtS, int E, int CS, int NB) {
    __shared__ int lcur[256];
    int c = blockIdx.x, t = threadIdx.x;
    const int* key = blockIdx.y ? eidx : (eidx + E);
    const int* val = blockIdx.y ? (eidx + E) : eidx;
    const int* go  = blockIdx.y ? goS : goD;
    unsigned int* srt = blockIdx.y ? srtS : srtD;
    if (t < NB) lcur[t] = go[t * NCH + c];
    __syncthreads();
    int s = c * CS, e = min(E, s + CS);
    for (int i = s + t; i < e; i += 256) {
        int k = key[i];
        int pos = atomicAdd(&lcur[k >> 8], 1);
        srt[pos] = ((unsigned int)(k & 255) << 16) | (unsigned int)val[i];   // N <= 65536
    }
}

// ---------------- B: per-bucket degree + row_ptr + CSR fill; fwd also dinv/xs4 ----------
__global__ void k_build(const unsigned int* __restrict__ srtD, const unsigned int* __restrict__ srtS,
                        const int* __restrict__ bsD, const int* __restrict__ bsS,
                        int* __restrict__ rpD, int* __restrict__ rpS,
                        int* __restrict__ colD, int* __restrict__ colS,
                        float* __restrict__ dinv, const float* __restrict__ x,
                        float4* __restrict__ xs4, int N, int NB) {
    __shared__ int lcnt[256];
    __shared__ int lpos[256];
    __shared__ int lds1[4];
    int nb = blockIdx.x, t = threadIdx.x;
    bool rev = blockIdx.y != 0;
    const unsigned int* srt = rev ? srtS : srtD;
    const int* bst = rev ? bsS : bsD;
    int* rp  = rev ? rpS : rpD;
    int* col = rev ? colS : colD;
    lcnt[t] = 0; __syncthreads();
    int s = bst[nb], e = bst[nb + 1];
    for (int i = s + t; i < e; i += 256) atomicAdd(&lcnt[srt[i] >> 16], 1);
    __syncthreads();
    int c = lcnt[t];
    int cx = exclScan256(c, lds1, t);
    int rpv = s + cx;
    int node = (nb << 8) + t;
    rp[node] = rpv;
    lpos[t] = rpv;
    if (!rev && node < N) {
        float d = rsqrtf((float)(c + 1));   // +1 self-loop
        dinv[node] = d;
        float4 v;
        v.x = x[node * 3] * d; v.y = x[node * 3 + 1] * d; v.z = x[node * 3 + 2] * d; v.w = 0.f;
        xs4[node] = v;
    }
    __syncthreads();
    for (int i = s + t; i < e; i += 256) {
        unsigned int v = srt[i];
        int p = atomicAdd(&lpos[v >> 16], 1);
        col[p] = (int)(v & 0xffffu);
    }
}

// ---------------- layer 1: 16 lanes/node; store g1=(agg,di) + y ----------------
__global__ void k_y(const float4* __restrict__ xs4, const int* __restrict__ rpD,
                    const int* __restrict__ colD, const float* __restrict__ dinv,
                    const float* __restrict__ W1, const float* __restrict__ b1,
                    const float* __restrict__ small, float4* __restrict__ g1,
                    float* __restrict__ y, int N) {
    int t = threadIdx.x;
    int sub = t & 15;
    int node = blockIdx.x * 16 + (t >> 4);
    if (node >= N) return;
    float di = dinv[node];
    int s = rpD[node], e = rpD[node + 1];
    float a0 = 0.f, a1 = 0.f, a2 = 0.f;
    for (int j = s + sub; j < e; j += 16) {
        float4 xv = xs4[colD[j]];
        a0 += xv.x; a1 += xv.y; a2 += xv.z;
    }
    if (sub == 0) { float4 xv = xs4[node]; a0 += xv.x; a1 += xv.y; a2 += xv.z; }
#pragma unroll
    for (int off = 1; off < 16; off <<= 1) {
        a0 += __shfl_xor(a0, off);
        a1 += __shfl_xor(a1, off);
        a2 += __shfl_xor(a2, off);
    }
    a0 *= di; a1 *= di; a2 *= di;
    float yl = 0.f;
#pragma unroll
    for (int m = 0; m < 8; ++m) {
        int c = sub * 8 + m;
        float h = fmaxf(a0 * W1[c] + a1 * W1[128 + c] + a2 * W1[256 + c] + b1[c], 0.f);
        yl += h * small[c];
    }
#pragma unroll
    for (int off = 1; off < 16; off <<= 1) yl += __shfl_xor(yl, off);
    if (sub == 0) {
        y[node] = yl * di;
        float4 gv; gv.x = a0; gv.y = a1; gv.z = a2; gv.w = di;
        g1[node] = gv;
    }
}

// ---------------- dv/rel: scalar aggregation of y over dst-CSR ----------------
__global__ void k_dv(const float* __restrict__ y, const int* __restrict__ rpD,
                     const int* __restrict__ colD, const float* __restrict__ dinv,
                     const float* __restrict__ small, float* __restrict__ relw,
                     float* __restrict__ rel, int N) {
    int t = threadIdx.x;
    int sub = t & 15;
    int node = blockIdx.x * 16 + (t >> 4);
    if (node >= N) return;
    float di = dinv[node];
    int s = rpD[node], e = rpD[node + 1];
    float acc = (sub == 0) ? y[node] : 0.f;
    for (int j = s + sub; j < e; j += 16) acc += y[colD[j]];
#pragma unroll
    for (int off = 1; off < 16; off <<= 1) acc += __shfl_xor(acc, off);
    float z = (acc * di + small[128]) * 0.125f;     // / sqrt(64)
    float r = 1.f / (1.f + __expf(-z));
    if (sub == 0) { rel[node] = r; relw[node] = r * di; }
}

// ---------------- z + S: z[u]=relw[u]+sum_{u->n}relw[n]; S += z[u]*dinv[u]*h1[u] ----------
__global__ void k_z(const float4* __restrict__ g1, const int* __restrict__ rpS,
                    const int* __restrict__ colS, const float* __restrict__ relw,
                    const float* __restrict__ rel, const float* __restrict__ W1,
                    const float* __restrict__ b1, float* __restrict__ part, int N) {
    __shared__ float W1s[384];
    __shared__ float b1s[128];
    __shared__ float sS[4][132];
    int t = threadIdx.x, lane = t & 63, wid = t >> 6;
    int sub = lane & 15;
    if (t < 128) { W1s[t] = W1[t]; W1s[128 + t] = W1[128 + t]; W1s[256 + t] = W1[256 + t];
                   b1s[t] = b1[t]; }
    __syncthreads();
    float acc[8];
#pragma unroll
    for (int m = 0; m < 8; ++m) acc[m] = 0.f;
    float Racc = 0.f;
    for (int node = blockIdx.x * 16 + (t >> 4); node < N; node += ZB * 16) {
        int s = rpS[node], e = rpS[node + 1];
        float w = (sub == 0) ? relw[node] : 0.f;
        for (int j = s + sub; j < e; j += 16) w += relw[colS[j]];
#pragma unroll
        for (int off = 1; off < 16; off <<= 1) w += __shfl_xor(w, off);
        float4 gv = g1[node];
        float zw = w * gv.w;                       // z * dinv
#pragma unroll
        for (int m = 0; m < 8; ++m) {
            int c = sub * 8 + m;
            float h = fmaxf(gv.x * W1s[c] + gv.y * W1s[128 + c] + gv.z * W1s[256 + c] + b1s[c], 0.f);
            acc[m] += zw * h;
        }
        if (sub == 0) Racc += rel[node];
    }
#pragma unroll
    for (int m = 0; m < 8; ++m) {
        acc[m] += __shfl_xor(acc[m], 16);
        acc[m] += __shfl_xor(acc[m], 32);
    }
    Racc += __shfl_xor(Racc, 16);
    Racc += __shfl_xor(Racc, 32);
    if (lane < 16) {
#pragma unroll
        for (int m = 0; m < 8; ++m) sS[wid][sub * 8 + m] = acc[m];
    }
    if (lane == 0) sS[wid][128] = Racc;
    __syncthreads();
    if (t < 129) part[blockIdx.x * 132 + t] = sS[0][t] + sS[1][t] + sS[2][t] + sS[3][t];
}

// ---------------- tail: reduce part -> S,R; newT = trainOT + (S@W2+R*b2)@Wv + R*bv --------
__global__ void k_tailred(const float* __restrict__ trainOT, const float* __restrict__ W2,
                          const float* __restrict__ b2, const float* __restrict__ Wv,
                          const float* __restrict__ bv, const float* __restrict__ part,
                          float* __restrict__ small, float* __restrict__ out_tail) {
    __shared__ float acc8[1024];
    __shared__ float Ss[129];
    __shared__ float t1[128];
    __shared__ float r8[8];
    int t = threadIdx.x;            // 1024
    int c = t >> 3, sl = t & 7;     // 128 cols x 8 slices
    float s = 0.f;
    for (int b = sl; b < ZB; b += 8) s += part[b * 132 + c];
    acc8[t] = s;
    if (t < 8) {
        float r = 0.f;
        for (int b = t; b < ZB; b += 8) r += part[b * 132 + 128];
        r8[t] = r;
    }
    __syncthreads();
    if (t < 128) {
        float v = 0.f;
#pragma unroll
        for (int k = 0; k < 8; ++k) v += acc8[t * 8 + k];
        Ss[t] = v;
    }
    if (t == 0) Ss[128] = r8[0] + r8[1] + r8[2] + r8[3] + r8[4] + r8[5] + r8[6] + r8[7];
    __syncthreads();
    float R = Ss[128];
    int o = t & 127, s2 = t >> 7;   // 8 K-slices of 16
    float a1 = 0.f;
#pragma unroll
    for (int j = s2 * 16; j < s2 * 16 + 16; ++j) a1 += Ss[j] * W2[j * 128 + o];
    acc8[t] = a1; __syncthreads();
    if (t < 128) {
        float v = R * b2[t];
#pragma unroll
        for (int k = 0; k < 8; ++k) v += acc8[t + 128 * k];
        t1[t] = v;
    }
    __syncthreads();
    float a2 = 0.f;
#pragma unroll
    for (int j = s2 * 16; j < s2 * 16 + 16; ++j) a2 += t1[j] * Wv[j * 128 + o];
    acc8[t] = a2; __syncthreads();
    if (t < 128) {
        float v = R * bv[t];
#pragma unroll
        for (int k = 0; k < 8; ++k) v += acc8[t + 128 * k];
        float nt = trainOT[t] + v;
        small[264 + t] = nt;
        out_tail[t] = nt;
    }
}

// ---------------- speak: out[j] = newT @ Ws[:,j] + bs[j], 4 K-slices, LDS reduce ----------
__global__ void k_speak(const float* __restrict__ Ws, const float* __restrict__ bs,
                        const float* __restrict__ small, float* __restrict__ out, int out_n) {
    __shared__ float nt[128];
    __shared__ float s0[256], s1[256];
    int t = threadIdx.x;
    if (t < 128) nt[t] = small[264 + t];
    __syncthreads();
    int jj = (t & 63) * 2, sl = t >> 6;       // 4 K-slices of 32
    int j = blockIdx.x * 128 + jj;
    float a0 = 0.f, a1 = 0.f;
    if (j < out_n) {
        const float* w = Ws + (size_t)(sl * 32) * out_n + j;
        for (int k = 0; k < 32; ++k) {
            float cv = nt[sl * 32 + k];
            float2 r = *reinterpret_cast<const float2*>(w + (size_t)k * out_n);
            a0 += cv * r.x; a1 += cv * r.y;
        }
    }
    s0[t] = a0; s1[t] = a1; __syncthreads();
    if (t < 64 && j < out_n) {
        out[j]     = s0[t] + s0[t + 64] + s0[t + 128] + s0[t + 192] + bs[j];
        out[j + 1] = s1[t] + s1[t + 64] + s1[t + 128] + s1[t + 192] + bs[j + 1];
    }
}

extern "C" void kernel_launch(void* const* d_in, const int* in_sizes, int n_in,
                              void* d_out, int out_size, void* d_ws, size_t ws_size,
                              hipStream_t stream) {
    const float* features = (const float*)d_in[0];
    const int*   eidx     = (const int*)d_in[1];
    const float* trainOT  = (const float*)d_in[2];
    const float* W1 = (const float*)d_in[3];
    const float* b1 = (const float*)d_in[4];
    const float* W2 = (const float*)d_in[5];
    const float* b2 = (const float*)d_in[6];
    const float* Wq = (const float*)d_in[7];
    const float* bq = (const float*)d_in[8];
    const float* Wk = (const float*)d_in[9];
    const float* bk = (const float*)d_in[10];
    const float* Wv = (const float*)d_in[11];
    const float* bv = (const float*)d_in[12];
    const float* Ws = (const float*)d_in[13];
    const float* bs = (const float*)d_in[14];

    int N = in_sizes[0] / 3;
    int E = in_sizes[1] / 2;
    int NB = (N + 255) >> 8;
    int CS = (E + NCH - 1) / NCH;

    char* ws = (char*)d_ws;
    float* small = (float*)(ws + O_SMALL);
    int*   rpD   = (int*)(ws + O_RPD);
    int*   rpS   = (int*)(ws + O_RPS);
    float* dinv  = (float*)(ws + O_DINV);
    float* y     = (float*)(ws + O_Y);
    float* relw  = (float*)(ws + O_RELW);
    float* rel   = (float*)(ws + O_REL);
    int*   bsD   = (int*)(ws + O_BSD);
    int*   bsS   = (int*)(ws + O_BSS);
    float* part  = (float*)(ws + O_PART);
    float4* xs4  = (float4*)(ws + O_XS);
    float4* g1   = (float4*)(ws + O_G1);
    int*   ghD   = (int*)(ws + O_GHD);
    int*   ghS   = (int*)(ws + O_GHS);
    int*   goD   = (int*)(ws + O_GOD);
    int*   goS   = (int*)(ws + O_GOS);
    unsigned int* srtD = (unsigned int*)(ws + O_SRTD);
    unsigned int* srtS = (unsigned int*)(ws + O_SRTS);
    int*   colD  = (int*)(ws + O_COLD);
    int*   colS  = (int*)(ws + O_COLS);
    float* out   = (float*)d_out;
    int out_n = out_size - 128;

    k_hist<<<dim3(NCH, 2), 256, 0, stream>>>(eidx, ghD, ghS, E, CS, NB);
    k_goff<<<dim3(NB + 1, 2), 256, 0, stream>>>(ghD, ghS, goD, goS, bsD, bsS,
                                                trainOT, Wq, bq, Wk, bk, W2, b2, small, E, NB);
    k_scatter<<<dim3(NCH, 2), 256, 0, stream>>>(eidx, goD, goS, srtD, srtS, E, CS, NB);
    k_build<<<dim3(NB, 2), 256, 0, stream>>>(srtD, srtS, bsD, bsS, rpD, rpS, colD, colS,
                                             dinv, features, xs4, N, NB);
    k_y<<<(N + 15) / 16, 256, 0, stream>>>(xs4, rpD, colD, dinv, W1, b1, small, g1, y, N);
    k_dv<<<(N + 15) / 16, 256, 0, stream>>>(y, rpD, colD, dinv, small, relw, rel, N);
    k_z<<<ZB, 256, 0, stream>>>(g1, rpS, colS, relw, rel, W1, b1, part, N);
    k_tailred<<<1, 1024, 0, stream>>>(trainOT, W2, b2, Wv, bv, part, small, out + out_n);
    k_speak<<<(out_n + 127) / 128, 256, 0, stream>>>(Ws, bs, small, out, out_n);
}